// Round 5
// baseline (972.819 us; speedup 1.0000x reference)
//
#include <hip/hip_runtime.h>

// R5 = R3 (correct output kernel) + a DIAGNOSTIC streaming-store probe over
// the full 4.295 GB d_ws. The probe uses the same compute+store structure and
// is byte-comparable to the harness's fillBufferAligned dispatches (which hit
// 6.5-6.6 TB/s). It writes disjoint lines once (no L2 rewrite absorption), so
// its rocprof counters give our structure's true steady-state write rate.
// Deterministic: same values into d_ws every call.

#define ALIBI_S 4096
#define ALIBI_H 16
#define UNROLL  16
#define BLOCK   256

typedef float f32x4 __attribute__((ext_vector_type(4)));

__global__ __launch_bounds__(BLOCK) void alibi_bias_kernel(
    const float* __restrict__ slopes,
    f32x4* __restrict__ out)
{
    const int h = blockIdx.y;
    const float ns = -slopes[h];

    const unsigned int base_f4 = blockIdx.x * (BLOCK * UNROLL) + threadIdx.x;
    f32x4* plane = out + ((size_t)h << 22);

#pragma unroll
    for (int k = 0; k < UNROLL; ++k) {
        const unsigned int f = base_f4 + (unsigned int)k * BLOCK;
        const unsigned int e = f << 2;
        const int i = (int)(e >> 12);
        const int j = (int)(e & 4095u);

        f32x4 v;
        v.x = (j + 0 > i) ? ns * (float)(j + 0 - i) : 0.0f;
        v.y = (j + 1 > i) ? ns * (float)(j + 1 - i) : 0.0f;
        v.z = (j + 2 > i) ? ns * (float)(j + 2 - i) : 0.0f;
        v.w = (j + 3 > i) ? ns * (float)(j + 3 - i) : 0.0f;

        plane[f] = v;
    }
}

// Diagnostic: same compute+store structure, streamed over n4 float4s of ws.
__global__ __launch_bounds__(BLOCK) void ws_probe_kernel(
    const float* __restrict__ slopes,
    f32x4* __restrict__ ws,
    size_t n4)
{
    const size_t base_f4 = (size_t)blockIdx.x * (BLOCK * UNROLL) + threadIdx.x;

#pragma unroll
    for (int k = 0; k < UNROLL; ++k) {
        const size_t f = base_f4 + (size_t)k * BLOCK;
        if (f >= n4) return;
        const unsigned int e = (unsigned int)(f << 2);   // wraps mod 2^32: fine, it's a pattern
        const int h = (int)((f >> 22) & 15u);
        const float ns = -slopes[h];
        const int i = (int)((e >> 12) & 4095u);
        const int j = (int)(e & 4095u);

        f32x4 v;
        v.x = (j + 0 > i) ? ns * (float)(j + 0 - i) : 0.0f;
        v.y = (j + 1 > i) ? ns * (float)(j + 1 - i) : 0.0f;
        v.z = (j + 2 > i) ? ns * (float)(j + 2 - i) : 0.0f;
        v.w = (j + 3 > i) ? ns * (float)(j + 3 - i) : 0.0f;

        ws[f] = v;
    }
}

extern "C" void kernel_launch(void* const* d_in, const int* in_sizes, int n_in,
                              void* d_out, int out_size, void* d_ws, size_t ws_size,
                              hipStream_t stream) {
    const float* slopes = (const float*)d_in[0];
    f32x4* out = (f32x4*)d_out;

    // Correct output kernel (the real work).
    dim3 grid(ALIBI_S * ALIBI_S / 4 / (BLOCK * UNROLL), ALIBI_H);
    alibi_bias_kernel<<<grid, BLOCK, 0, stream>>>(slopes, out);

    // Diagnostic probe over the whole workspace.
    const size_t n4 = ws_size / 16;
    if (n4 > 0) {
        const unsigned int nblocks = (unsigned int)((n4 + (BLOCK * UNROLL) - 1) / (BLOCK * UNROLL));
        ws_probe_kernel<<<nblocks, BLOCK, 0, stream>>>(slopes, (f32x4*)d_ws, n4);
    }
}

// Round 6
// 185.726 us; speedup vs baseline: 5.2379x; 5.2379x over previous
//
#include <hip/hip_runtime.h>

// ALiBi bias: out[h,i,j] = (j > i) ? -slopes[h]*(j-i) : 0
// H=16, S=4096, float32 [16,4096,4096] = 1.074 GB. Pure write-BW-bound.
//
// R6: fill-mimic structure. rocprof R5 probe showed our 16K-block version
// sustains only 5.3 TB/s steady-state while rocclr fillBufferAligned does
// 6.6 TB/s at OccupancyPercent=10.6% (~1 block/CU). Theory: HBM write
// efficiency needs few, dense, sequentially-marching write streams; thousands
// of interleaved 1KB bursts thrash row buffers. So: 256 blocks x 256 threads
// (1 block/CU), flat grid-stride -> dense 1 MB instantaneous window marching
// through the buffer, 1024 iterations/thread.

#define ALIBI_S 4096
#define ALIBI_H 16
#define BLOCK   256
#define GRID    256          // 1 block per CU
#define N_F4    (1u << 26)   // H*S*S/4 float4 elements
#define STRIDE  (GRID * BLOCK)          // 65536 float4s = 1 MB per sweep
#define ITERS   (N_F4 / STRIDE)         // 1024

typedef float f32x4 __attribute__((ext_vector_type(4)));

__global__ __launch_bounds__(BLOCK) void alibi_bias_kernel(
    const float* __restrict__ slopes,
    f32x4* __restrict__ out)
{
    __shared__ float ns_s[ALIBI_H];
    if (threadIdx.x < ALIBI_H) ns_s[threadIdx.x] = -slopes[threadIdx.x];
    __syncthreads();

    unsigned int f = blockIdx.x * BLOCK + threadIdx.x;  // float4 index

#pragma unroll 4
    for (int it = 0; it < ITERS; ++it, f += STRIDE) {
        const unsigned int e = f << 2;           // element index (max 2^28)
        const int h = (int)(e >> 24);            // plane (wave-uniform; LDS broadcast)
        const float ns = ns_s[h];
        const int i = (int)((e >> 12) & 4095u);  // row
        const int j = (int)(e & 4095u);          // first of 4 consecutive cols

        f32x4 v;
        v.x = (j + 0 > i) ? ns * (float)(j + 0 - i) : 0.0f;
        v.y = (j + 1 > i) ? ns * (float)(j + 1 - i) : 0.0f;
        v.z = (j + 2 > i) ? ns * (float)(j + 2 - i) : 0.0f;
        v.w = (j + 3 > i) ? ns * (float)(j + 3 - i) : 0.0f;

        out[f] = v;
    }
}

extern "C" void kernel_launch(void* const* d_in, const int* in_sizes, int n_in,
                              void* d_out, int out_size, void* d_ws, size_t ws_size,
                              hipStream_t stream) {
    const float* slopes = (const float*)d_in[0];
    f32x4* out = (f32x4*)d_out;
    alibi_bias_kernel<<<GRID, BLOCK, 0, stream>>>(slopes, out);
}